// Round 5
// baseline (360.142 us; speedup 1.0000x reference)
//
#include <hip/hip_runtime.h>

typedef unsigned short u16;
typedef unsigned int u32;
typedef __attribute__((ext_vector_type(8))) short bf16x8;
typedef __attribute__((ext_vector_type(4))) float f32x4;

#define B_TOT 16384
#define RR 16
#define NBLK (B_TOT / RR)
#define TT 30
#define LL 100
#define DTC 0.03f
#define L2E 1.44269504088896f

#define HST 104              // u16 stride of H rows (K=96 + pad), 16B aligned
#define HBUF_U16 (RR * HST)  // 1664 u16 per buffer

// ---- LDS byte offsets, total 19456 ----
#define OFF_H   0        // u16 [2][16][104] = 6656
#define OFF_XB  6656     // u16 [2][16][72] = 4608; sRaw f32[1920] aliases 6656..14335 at staging;
                         // sPrev f32[16][4] (+0) and sWc f32[2][64] (+256) alias here in decoder
#define OFF_Z   11264    // u16 [16][136] = 4352
#define OFF_U   15616    // 3840: inp bf16[16][30][4] (encoder) -> muBuf bf16[16][100] (MLP)
#define SMEM_SZ 19456

// ---- d_ws u16 offsets ----
#define WS_WHHE  0        // [256][72]: cols0-63 whh*scale, 64-67 fold, 68 bias, 69-71 zero
#define WS_WHHD  18432
#define WS_MWS   36864    // mean_Ws 3x[64][64]
#define WS_LWS   49152
#define WS_MWF   61440    // [100][64]
#define WS_LWF   67840
#define WS_WINIT 74240    // [64][128] zero-padded
#define WS_TOTAL 82432    // u16 (164864 bytes)

__device__ __forceinline__ float bf2f(u16 u) {
    union { u32 i; float f; } v; v.i = ((u32)u) << 16; return v.f;
}
__device__ __forceinline__ u16 f2bf(float f) {
    union { float f; u32 i; } v; v.f = f;
    return (u16)((v.i + 0x7FFFu + ((v.i >> 16) & 1u)) >> 16);
}
__device__ __forceinline__ float rcpf(float x) { return __builtin_amdgcn_rcpf(x); }
__device__ __forceinline__ float ex2(float x) { return __builtin_amdgcn_exp2f(x); }
__device__ __forceinline__ float tanh_(float x) {
    x = fminf(fmaxf(x, -15.f), 15.f);
    float e = __expf(2.f * x);
    return (e - 1.f) * rcpf(e + 1.f);
}
__device__ __forceinline__ float leaky(float x) { return x >= 0.f ? x : 0.01f * x; }
__device__ __forceinline__ f32x4 mfma16(bf16x8 a, bf16x8 b, f32x4 c) {
    return __builtin_amdgcn_mfma_f32_16x16x32_bf16(a, b, c, 0, 0, 0);
}

// ================= setup kernel: weight prep into d_ws =================
__global__ void setup_kernel(
    const float* __restrict__ W_se, const float* __restrict__ b_se,
    const float* __restrict__ W_ih_e, const float* __restrict__ W_hh_e,
    const float* __restrict__ b_ih_e, const float* __restrict__ b_hh_e,
    const float* __restrict__ W_ih_d, const float* __restrict__ W_hh_d,
    const float* __restrict__ b_ih_d, const float* __restrict__ b_hh_d,
    const float* __restrict__ mean_Ws, const float* __restrict__ lv_Ws,
    const float* __restrict__ mean_Wf, const float* __restrict__ lv_Wf,
    const float* __restrict__ W_init, u16* __restrict__ ws)
{
    const int gid = blockIdx.x * 256 + threadIdx.x;
    const int nth = gridDim.x * 256;
    // A: folded input-proj tails (512 dot-tasks)
    for (int i = gid; i < 512; i += nth) {
        int which = i >> 8, row = i & 255, g = row >> 6;
        float s = (g == 2) ? 2.f * L2E : L2E;
        const float* wih = (which ? W_ih_d : W_ih_e) + row * 64;
        float f0=0,f1=0,f2=0,f3=0,fb=0;
        for (int e = 0; e < 64; ++e) {
            float w = wih[e];
            f0 = fmaf(w, W_se[e*4+0], f0);
            f1 = fmaf(w, W_se[e*4+1], f1);
            f2 = fmaf(w, W_se[e*4+2], f2);
            f3 = fmaf(w, W_se[e*4+3], f3);
            fb = fmaf(w, b_se[e], fb);
        }
        fb += (which ? b_ih_d : b_ih_e)[row] + (which ? b_hh_d : b_hh_e)[row];
        u16* dst = ws + (which ? WS_WHHD : WS_WHHE) + row * 72 + 64;
        dst[0]=f2bf(f0*s); dst[1]=f2bf(f1*s); dst[2]=f2bf(f2*s); dst[3]=f2bf(f3*s);
        dst[4]=f2bf(fb*s); dst[5]=0; dst[6]=0; dst[7]=0;
    }
    // B: scaled W_hh rows
    for (int i = gid; i < 2*16384; i += nth) {
        int which = i >= 16384;
        int j = which ? i - 16384 : i;
        int row = j >> 6, k = j & 63, g = row >> 6;
        float s = (g == 2) ? 2.f * L2E : L2E;
        const float* whh = which ? W_hh_d : W_hh_e;
        ws[(which ? WS_WHHD : WS_WHHE) + row*72 + k] = f2bf(whh[j] * s);
    }
    // C: MLP hidden weights
    for (int i = gid; i < 12288; i += nth) {
        ws[WS_MWS + i] = f2bf(mean_Ws[i]);
        ws[WS_LWS + i] = f2bf(lv_Ws[i]);
    }
    // D: MLP final weights
    for (int i = gid; i < 6400; i += nth) {
        ws[WS_MWF + i] = f2bf(mean_Wf[i]);
        ws[WS_LWF + i] = f2bf(lv_Wf[i]);
    }
    // E: W_init zero-padded [64][128]
    for (int i = gid; i < 8192; i += nth) {
        int r = i >> 7, k = i & 127;
        ws[WS_WINIT + i] = (k < LL) ? f2bf(W_init[r*LL + k]) : (u16)0;
    }
}

// ================= main fused kernel =================
__global__ __launch_bounds__(256, 8) void vae_lstm_kernel(
    const float* __restrict__ expert, const float* __restrict__ init_state,
    const float* __restrict__ eps, const u16* __restrict__ ws,
    const float* __restrict__ mean_bs, const float* __restrict__ mean_bf,
    const float* __restrict__ lv_bs, const float* __restrict__ lv_bf,
    const float* __restrict__ b_init, const float* __restrict__ W_c,
    const float* __restrict__ b_c,
    float* __restrict__ out_recons, float* __restrict__ out_expert,
    float* __restrict__ out_mu, float* __restrict__ out_lv)
{
    const int tid = threadIdx.x;
    const int b0g = blockIdx.x * RR;
    const int wv = tid >> 6;
    const int lane = tid & 63;
    const int lcol = lane & 15;
    const int quad = lane >> 4;
    const int jcol = wv * 16 + lcol;

    __shared__ __align__(16) char smem[SMEM_SZ];
    u16* Hbuf  = (u16*)(smem + OFF_H);
    u16* XB0   = (u16*)(smem + OFF_XB);
    u16* XB1   = XB0 + RR * 72;
    u16* zBuf  = (u16*)(smem + OFF_Z);
    u16* inp   = (u16*)(smem + OFF_U);
    u16* muB   = (u16*)(smem + OFF_U);      // alias: inp dead after encoder
    float* sRaw  = (float*)(smem + OFF_XB); // staging alias
    float* sPrev = (float*)(smem + OFF_XB); // decoder alias (XB dead)
    float* sWc   = (float*)(smem + OFF_XB + 256);

    // ---- staging: load raw (+passthrough), zero H, rel-xy -> inp ----
    {
        const int base = b0g * (TT*4);
        u32* hz = (u32*)Hbuf;
        for (int idx = tid; idx < HBUF_U16; idx += 256) hz[idx] = 0;   // bytes 0..6655 = both H buffers
        for (int idx = tid; idx < RR*TT*4; idx += 256) {
            float v = expert[base + idx];
            sRaw[idx] = v;
            out_expert[base + idx] = v;
        }
        __syncthreads();
        for (int idx = tid; idx < RR*TT*4; idx += 256) {
            int q = idx % (TT*4);
            int k = q & 3, t = q >> 2;
            int row = idx / (TT*4);
            float v = sRaw[idx];
            if (k < 2 && t > 0) v -= sRaw[idx - 4];
            u16 hv = f2bf(v);
            inp[idx] = hv;
            if (t == 0) Hbuf[row*HST + 64 + k] = hv;
            if (q == 0) {
                Hbuf[row*HST + 68] = 0x3F80;                 // 1.0 (bias column)
                Hbuf[HBUF_U16 + row*HST + 68] = 0x3F80;
            }
        }
        __syncthreads();
    }

    float creg[4] = {0.f, 0.f, 0.f, 0.f};
    bf16x8 bw[4][3];

    auto build_bw = [&](const u16* wsW) {
#pragma unroll
        for (int g = 0; g < 4; ++g) {
            const u16* wr = wsW + (g*64 + jcol) * 72;
            bw[g][0] = *(const bf16x8*)(wr + quad*8);
            bw[g][1] = *(const bf16x8*)(wr + 32 + quad*8);
            if (quad == 0) {
                bw[g][2] = *(const bf16x8*)(wr + 64);
            } else {
                bf16x8 z;
#pragma unroll
                for (int j = 0; j < 8; ++j) z[j] = 0;
                bw[g][2] = z;
            }
        }
    };

    // one LSTM step: MFMA K=96 (h | x | 1 | 0) ; gates pre-scaled by log2e (g by 2log2e)
    auto lstm_step = [&](const u16* Hc, u16* Hn) {
        bf16x8 a0 = *(const bf16x8*)(Hc + lcol*HST + quad*8);
        bf16x8 a1 = *(const bf16x8*)(Hc + lcol*HST + 32 + quad*8);
        bf16x8 a2 = *(const bf16x8*)(Hc + lcol*HST + 64 + quad*8);
        f32x4 acc[4];
#pragma unroll
        for (int g = 0; g < 4; ++g) {
            f32x4 z = {0.f, 0.f, 0.f, 0.f};
            z = mfma16(a0, bw[g][0], z);
            z = mfma16(a1, bw[g][1], z);
            acc[g] = mfma16(a2, bw[g][2], z);
        }
#pragma unroll
        for (int r = 0; r < 4; ++r) {
            float Ei = ex2(-acc[0][r]);              // exp(-i)
            float Ef = ex2(-acc[1][r]);              // exp(-f)
            float Eg = ex2(-acc[2][r]);              // exp(-2g)
            float Eo = ex2(-acc[3][r]);              // exp(-o)
            float P = (1.f + Ei) * (1.f + Eg);
            float Q = 1.f + Ef;
            // c' = c*sigm(f) + sigm(i)*tanh(g) = [c*P + (1-Eg)*Q] / (P*Q)
            float num = fmaf(creg[r], P, (1.f - Eg) * Q);
            float c = num * rcpf(P * Q);
            creg[r] = c;
            float Ec = ex2(-2.f * L2E * c);          // exp(-2c)
            float h = (1.f - Ec) * rcpf((1.f + Eo) * (1.f + Ec));
            Hn[(quad*4 + r)*HST + jcol] = f2bf(h);
        }
    };

    // ---- encoder ----
    build_bw(ws + WS_WHHE);
    for (int stp = 0; stp < TT; ++stp) {
        const u16* Hc = Hbuf + (stp & 1) * HBUF_U16;
        u16* Hn = Hbuf + ((stp + 1) & 1) * HBUF_U16;
        lstm_step(Hc, Hn);
        if (tid < 64 && stp < TT-1) {
            int row = tid >> 2, k = tid & 3;
            Hn[row*HST + 64 + k] = inp[row*(TT*4) + (stp+1)*4 + k];
        }
        __syncthreads();
    }
    // hT in Hbuf[0] (TT even)

    // zero zBuf (pad cols >= 100 must be 0)
    {
        u32* zb = (u32*)zBuf;
        for (int idx = tid; idx < RR*136/2; idx += 256) zb[idx] = 0;
    }

    auto mlp_hidden = [&](const u16* inB, int inStride, u16* outB,
                          const u16* wsW, const float* bg) {
        float bv = bg[jcol];
        const u16* wr = wsW + jcol*64;
        bf16x8 bb0 = *(const bf16x8*)(wr + quad*8);
        bf16x8 bb1 = *(const bf16x8*)(wr + 32 + quad*8);
        f32x4 acc = {bv, bv, bv, bv};
        bf16x8 a0 = *(const bf16x8*)(inB + lcol*inStride + quad*8);
        bf16x8 a1 = *(const bf16x8*)(inB + lcol*inStride + 32 + quad*8);
        acc = mfma16(a0, bb0, acc);
        acc = mfma16(a1, bb1, acc);
#pragma unroll
        for (int r = 0; r < 4; ++r)
            outB[(quad*4 + r)*72 + jcol] = f2bf(leaky(acc[r]));
        __syncthreads();
    };

    auto mlp_final = [&](const u16* inB, const u16* wsW, const float* bg, int mode) {
#pragma unroll
        for (int ni = 0; ni < 2; ++ni) {
            int nt = wv + ni*4;
            if (nt >= 7) continue;
            int n = nt*16 + lcol;
            bool ok = (n < LL);
            float bv = ok ? bg[n] : 0.f;
            bf16x8 bb0, bb1;
            if (ok) {
                const u16* wr = wsW + n*64;
                bb0 = *(const bf16x8*)(wr + quad*8);
                bb1 = *(const bf16x8*)(wr + 32 + quad*8);
            } else {
#pragma unroll
                for (int j = 0; j < 8; ++j) { bb0[j] = 0; bb1[j] = 0; }
            }
            f32x4 acc = {bv, bv, bv, bv};
            bf16x8 a0 = *(const bf16x8*)(inB + lcol*72 + quad*8);
            bf16x8 a1 = *(const bf16x8*)(inB + lcol*72 + 32 + quad*8);
            acc = mfma16(a0, bb0, acc);
            acc = mfma16(a1, bb1, acc);
            if (ok) {
#pragma unroll
                for (int r = 0; r < 4; ++r) {
                    int m = quad*4 + r;
                    float vv = leaky(acc[r]);
                    size_t gi = (size_t)(b0g + m) * LL + n;
                    if (mode == 0) {
                        muB[m*LL + n] = f2bf(vv);
                        out_mu[gi] = vv;
                    } else {
                        out_lv[gi] = vv;
                        float mu = bf2f(muB[m*LL + n]);
                        float zv = tanh_(fmaf(eps[gi], __expf(0.5f * vv), mu));
                        zBuf[m*136 + n] = f2bf(zv);
                    }
                }
            }
        }
        __syncthreads();
    };

    // mean path (hT intact in Hbuf[0])
    mlp_hidden(Hbuf, HST, XB0, ws + WS_MWS, mean_bs);
    mlp_hidden(XB0, 72, XB1, ws + WS_MWS + 4096, mean_bs + 64);
    mlp_hidden(XB1, 72, XB0, ws + WS_MWS + 8192, mean_bs + 128);
    mlp_final(XB0, ws + WS_MWF, mean_bf, 0);
    // logvar path + fused reparameterization
    mlp_hidden(Hbuf, HST, XB0, ws + WS_LWS, lv_bs);
    mlp_hidden(XB0, 72, XB1, ws + WS_LWS + 4096, lv_bs + 64);
    mlp_hidden(XB1, 72, XB0, ws + WS_LWS + 8192, lv_bs + 128);
    mlp_final(XB0, ws + WS_LWF, lv_bf, 1);

    // ---- dh = z @ W_init^T + b_init -> Hbuf[0] + creg; decoder prep ----
    {
        float bv = b_init[jcol];
        const u16* wr = ws + WS_WINIT + jcol*128;
        f32x4 acc = {bv, bv, bv, bv};
#pragma unroll
        for (int kt = 0; kt < 4; ++kt) {
            bf16x8 az = *(const bf16x8*)(zBuf + lcol*136 + kt*32 + quad*8);
            bf16x8 bi = *(const bf16x8*)(wr + kt*32 + quad*8);
            acc = mfma16(az, bi, acc);
        }
#pragma unroll
        for (int r = 0; r < 4; ++r) {
            creg[r] = acc[r];
            Hbuf[(quad*4 + r)*HST + jcol] = f2bf(acc[r]);
        }
        __syncthreads();   // zBuf reads done before sPrev/sWc overwrite XB region
        if (tid < RR*4) {
            float v = init_state[b0g*4 + tid];
            sPrev[tid] = v;
            Hbuf[(tid >> 2)*HST + 64 + (tid & 3)] = f2bf(v);
        }
        if (tid < 128) sWc[tid] = W_c[tid];
        __syncthreads();
    }

    build_bw(ws + WS_WHHD);
    const float bc0 = b_c[0], bc1 = b_c[1];

    // ---- decoder ----
    for (int stp = 0; stp < TT; ++stp) {
        const u16* Hc = Hbuf + (stp & 1) * HBUF_U16;
        u16* Hn = Hbuf + ((stp + 1) & 1) * HBUF_U16;
        lstm_step(Hc, Hn);
        __syncthreads();
        if (tid < 64) {
            int row = tid >> 2, kq = tid & 3;
            const u16* hr = Hn + row*HST + kq*16;
            bf16x8 h0 = *(const bf16x8*)(hr);
            bf16x8 h1 = *(const bf16x8*)(hr + 8);
            const float4* w0 = (const float4*)(sWc + kq*16);
            const float4* w1 = (const float4*)(sWc + 64 + kq*16);
            float a0 = 0.f, a1 = 0.f;
#pragma unroll
            for (int p = 0; p < 2; ++p) {
                float4 wa = w0[2*p], wb = w0[2*p+1];
                float4 va = w1[2*p], vb = w1[2*p+1];
                bf16x8 hh = p ? h1 : h0;
                float hf[8];
#pragma unroll
                for (int j = 0; j < 8; ++j) hf[j] = bf2f((u16)hh[j]);
                a0 = fmaf(hf[0], wa.x, a0); a0 = fmaf(hf[1], wa.y, a0);
                a0 = fmaf(hf[2], wa.z, a0); a0 = fmaf(hf[3], wa.w, a0);
                a0 = fmaf(hf[4], wb.x, a0); a0 = fmaf(hf[5], wb.y, a0);
                a0 = fmaf(hf[6], wb.z, a0); a0 = fmaf(hf[7], wb.w, a0);
                a1 = fmaf(hf[0], va.x, a1); a1 = fmaf(hf[1], va.y, a1);
                a1 = fmaf(hf[2], va.z, a1); a1 = fmaf(hf[3], va.w, a1);
                a1 = fmaf(hf[4], vb.x, a1); a1 = fmaf(hf[5], vb.y, a1);
                a1 = fmaf(hf[6], vb.z, a1); a1 = fmaf(hf[7], vb.w, a1);
            }
            a0 += __shfl_xor(a0, 1); a1 += __shfl_xor(a1, 1);
            a0 += __shfl_xor(a0, 2); a1 += __shfl_xor(a1, 2);
            if (kq == 0) {
                float pedal = a0 + bc0;
                float steer = fminf(fmaxf(a1 + bc1, -0.5f), 0.5f);
                float4 pv = *(const float4*)(sPrev + row*4);
                float x = pv.x, y = pv.y, psi = pv.z, v = pv.w;
                float v1 = fminf(fmaxf(v + pedal * DTC, 0.f), 30.f);
                float sn, cs;
                __sincosf(psi, &sn, &cs);
                float psid = fminf(fmaxf(v * __tanf(steer) * 0.4f, -1.57f), 1.57f);
                float nx = fmaf(v * cs, DTC, x);
                float ny = fmaf(v * sn, DTC, y);
                float npsi = fmaf(psid, DTC, psi);
                float4 o; o.x = nx; o.y = ny; o.z = npsi; o.w = v1;
                *(float4*)(sPrev + row*4) = o;
                *(float4*)(out_recons + ((size_t)(b0g + row) * TT + stp) * 4) = o;
                u32 lo = (u32)f2bf(nx) | ((u32)f2bf(ny) << 16);
                u32 hi = (u32)f2bf(npsi) | ((u32)f2bf(v1) << 16);
                uint2 pk; pk.x = lo; pk.y = hi;
                *(uint2*)(Hn + row*HST + 64) = pk;
            }
        }
        __syncthreads();
    }
}

extern "C" void kernel_launch(void* const* d_in, const int* in_sizes, int n_in,
                              void* d_out, int out_size, void* d_ws, size_t ws_size,
                              hipStream_t stream) {
    (void)in_sizes; (void)n_in; (void)ws_size; (void)out_size;
    const float* expert    = (const float*)d_in[0];
    const float* init_st   = (const float*)d_in[1];
    const float* eps       = (const float*)d_in[2];
    const float* W_se      = (const float*)d_in[3];
    const float* b_se      = (const float*)d_in[4];
    const float* W_ih_e    = (const float*)d_in[5];
    const float* W_hh_e    = (const float*)d_in[6];
    const float* b_ih_e    = (const float*)d_in[7];
    const float* b_hh_e    = (const float*)d_in[8];
    const float* mean_Ws   = (const float*)d_in[9];
    const float* mean_bs   = (const float*)d_in[10];
    const float* mean_Wf   = (const float*)d_in[11];
    const float* mean_bf   = (const float*)d_in[12];
    const float* lv_Ws     = (const float*)d_in[13];
    const float* lv_bs     = (const float*)d_in[14];
    const float* lv_Wf     = (const float*)d_in[15];
    const float* lv_bf     = (const float*)d_in[16];
    const float* W_init    = (const float*)d_in[17];
    const float* b_init    = (const float*)d_in[18];
    const float* W_ih_d    = (const float*)d_in[19];
    const float* W_hh_d    = (const float*)d_in[20];
    const float* b_ih_d    = (const float*)d_in[21];
    const float* b_hh_d    = (const float*)d_in[22];
    const float* W_c       = (const float*)d_in[23];
    const float* b_c       = (const float*)d_in[24];

    float* out = (float*)d_out;
    const size_t n_traj = (size_t)B_TOT * TT * 4;
    const size_t n_lat  = (size_t)B_TOT * LL;
    float* out_recons = out;
    float* out_expert = out + n_traj;
    float* out_mu     = out + 2 * n_traj;
    float* out_lv     = out + 2 * n_traj + n_lat;

    u16* ws = (u16*)d_ws;

    setup_kernel<<<64, 256, 0, stream>>>(
        W_se, b_se, W_ih_e, W_hh_e, b_ih_e, b_hh_e,
        W_ih_d, W_hh_d, b_ih_d, b_hh_d,
        mean_Ws, lv_Ws, mean_Wf, lv_Wf, W_init, ws);

    vae_lstm_kernel<<<NBLK, 256, 0, stream>>>(
        expert, init_st, eps, ws,
        mean_bs, mean_bf, lv_bs, lv_bf, b_init, W_c, b_c,
        out_recons, out_expert, out_mu, out_lv);
}

// Round 7
// 260.705 us; speedup vs baseline: 1.3814x; 1.3814x over previous
//
#include <hip/hip_runtime.h>

typedef unsigned short u16;
typedef unsigned int u32;
typedef __attribute__((ext_vector_type(8))) short bf16x8;
typedef __attribute__((ext_vector_type(4))) float f32x4;

#define B_TOT 16384
#define RR 16
#define NBLK (B_TOT / RR)
#define TT 30
#define LL 100
#define DTC 0.03f
#define L2E 1.44269504088896f

#define HST 104              // u16 stride of H rows (K=96 + pad), 16B aligned
#define HBUF_U16 (RR * HST)  // 1664 u16 per buffer

// ---- LDS byte offsets, total 19456 ----
#define OFF_H   0        // u16 [2][16][104] = 6656
#define OFF_XB  6656     // u16 [2][16][72] = 4608; sRaw f32[1920] aliases 6656..14335 at staging;
                         // sPrev f32[16][4] (+0) and sWc f32[2][64] (+256) alias here in decoder
#define OFF_Z   11264    // u16 [16][136] = 4352
#define OFF_U   15616    // 3840: inp bf16[16][30][4] (encoder) -> muBuf bf16[16][100] (MLP)
#define SMEM_SZ 19456

// ---- d_ws u16 offsets ----
#define WS_WHHE  0        // [256][72]: cols0-63 whh*scale, 64-67 fold, 68 bias, 69-71 zero
#define WS_WHHD  18432
#define WS_MWS   36864    // mean_Ws 3x[64][64]
#define WS_LWS   49152
#define WS_MWF   61440    // [100][64]
#define WS_LWF   67840
#define WS_WINIT 74240    // [64][128] zero-padded
#define WS_TOTAL 82432    // u16 (164864 bytes)

__device__ __forceinline__ float bf2f(u16 u) {
    union { u32 i; float f; } v; v.i = ((u32)u) << 16; return v.f;
}
__device__ __forceinline__ u16 f2bf(float f) {
    union { float f; u32 i; } v; v.f = f;
    return (u16)((v.i + 0x7FFFu + ((v.i >> 16) & 1u)) >> 16);
}
__device__ __forceinline__ float rcpf(float x) { return __builtin_amdgcn_rcpf(x); }
__device__ __forceinline__ float ex2(float x) { return __builtin_amdgcn_exp2f(x); }
__device__ __forceinline__ float tanh_(float x) {
    x = fminf(fmaxf(x, -15.f), 15.f);
    float e = __expf(2.f * x);
    return (e - 1.f) * rcpf(e + 1.f);
}
__device__ __forceinline__ float leaky(float x) { return x >= 0.f ? x : 0.01f * x; }
__device__ __forceinline__ f32x4 mfma16(bf16x8 a, bf16x8 b, f32x4 c) {
    return __builtin_amdgcn_mfma_f32_16x16x32_bf16(a, b, c, 0, 0, 0);
}

// ================= setup kernel: weight prep into d_ws =================
__global__ void setup_kernel(
    const float* __restrict__ W_se, const float* __restrict__ b_se,
    const float* __restrict__ W_ih_e, const float* __restrict__ W_hh_e,
    const float* __restrict__ b_ih_e, const float* __restrict__ b_hh_e,
    const float* __restrict__ W_ih_d, const float* __restrict__ W_hh_d,
    const float* __restrict__ b_ih_d, const float* __restrict__ b_hh_d,
    const float* __restrict__ mean_Ws, const float* __restrict__ lv_Ws,
    const float* __restrict__ mean_Wf, const float* __restrict__ lv_Wf,
    const float* __restrict__ W_init, u16* __restrict__ ws)
{
    const int gid = blockIdx.x * 256 + threadIdx.x;
    const int nth = gridDim.x * 256;
    // A: folded input-proj tails (512 dot-tasks)
    for (int i = gid; i < 512; i += nth) {
        int which = i >> 8, row = i & 255, g = row >> 6;
        float s = (g == 2) ? 2.f * L2E : L2E;
        const float* wih = (which ? W_ih_d : W_ih_e) + row * 64;
        float f0=0,f1=0,f2=0,f3=0,fb=0;
        for (int e = 0; e < 64; ++e) {
            float w = wih[e];
            f0 = fmaf(w, W_se[e*4+0], f0);
            f1 = fmaf(w, W_se[e*4+1], f1);
            f2 = fmaf(w, W_se[e*4+2], f2);
            f3 = fmaf(w, W_se[e*4+3], f3);
            fb = fmaf(w, b_se[e], fb);
        }
        fb += (which ? b_ih_d : b_ih_e)[row] + (which ? b_hh_d : b_hh_e)[row];
        u16* dst = ws + (which ? WS_WHHD : WS_WHHE) + row * 72 + 64;
        dst[0]=f2bf(f0*s); dst[1]=f2bf(f1*s); dst[2]=f2bf(f2*s); dst[3]=f2bf(f3*s);
        dst[4]=f2bf(fb*s); dst[5]=0; dst[6]=0; dst[7]=0;
    }
    // B: scaled W_hh rows
    for (int i = gid; i < 2*16384; i += nth) {
        int which = i >= 16384;
        int j = which ? i - 16384 : i;
        int row = j >> 6, k = j & 63, g = row >> 6;
        float s = (g == 2) ? 2.f * L2E : L2E;
        const float* whh = which ? W_hh_d : W_hh_e;
        ws[(which ? WS_WHHD : WS_WHHE) + row*72 + k] = f2bf(whh[j] * s);
    }
    // C: MLP hidden weights
    for (int i = gid; i < 12288; i += nth) {
        ws[WS_MWS + i] = f2bf(mean_Ws[i]);
        ws[WS_LWS + i] = f2bf(lv_Ws[i]);
    }
    // D: MLP final weights
    for (int i = gid; i < 6400; i += nth) {
        ws[WS_MWF + i] = f2bf(mean_Wf[i]);
        ws[WS_LWF + i] = f2bf(lv_Wf[i]);
    }
    // E: W_init zero-padded [64][128]
    for (int i = gid; i < 8192; i += nth) {
        int r = i >> 7, k = i & 127;
        ws[WS_WINIT + i] = (k < LL) ? f2bf(W_init[r*LL + k]) : (u16)0;
    }
}

// ================= main fused kernel =================
// launch_bounds(256,6): ~85-VGPR budget. Fragment set (bw[4][3] = 48 regs) compiled to
// 56 arch VGPRs in round 4 -> fits with NO spill. (256,8)'s 64-reg cap spilled (round 5:
// FETCH 9->252 MB). NOTE: no __builtin_amdgcn_mfma_f32_16x16x16_bf16 on gfx950 — K=32 only.
__global__ __launch_bounds__(256, 6) void vae_lstm_kernel(
    const float* __restrict__ expert, const float* __restrict__ init_state,
    const float* __restrict__ eps, const u16* __restrict__ ws,
    const float* __restrict__ mean_bs, const float* __restrict__ mean_bf,
    const float* __restrict__ lv_bs, const float* __restrict__ lv_bf,
    const float* __restrict__ b_init, const float* __restrict__ W_c,
    const float* __restrict__ b_c,
    float* __restrict__ out_recons, float* __restrict__ out_expert,
    float* __restrict__ out_mu, float* __restrict__ out_lv)
{
    const int tid = threadIdx.x;
    const int b0g = blockIdx.x * RR;
    const int wv = tid >> 6;
    const int lane = tid & 63;
    const int lcol = lane & 15;
    const int quad = lane >> 4;
    const int jcol = wv * 16 + lcol;

    __shared__ __align__(16) char smem[SMEM_SZ];
    u16* Hbuf  = (u16*)(smem + OFF_H);
    u16* XB0   = (u16*)(smem + OFF_XB);
    u16* XB1   = XB0 + RR * 72;
    u16* zBuf  = (u16*)(smem + OFF_Z);
    u16* inp   = (u16*)(smem + OFF_U);
    u16* muB   = (u16*)(smem + OFF_U);      // alias: inp dead after encoder
    float* sRaw  = (float*)(smem + OFF_XB); // staging alias
    float* sPrev = (float*)(smem + OFF_XB); // decoder alias (XB dead)
    float* sWc   = (float*)(smem + OFF_XB + 256);

    // ---- staging: load raw (+passthrough), zero H, rel-xy -> inp ----
    {
        const int base = b0g * (TT*4);
        u32* hz = (u32*)Hbuf;
        for (int idx = tid; idx < HBUF_U16; idx += 256) hz[idx] = 0;   // 6656 B = both H buffers
        for (int idx = tid; idx < RR*TT*4; idx += 256) {
            float v = expert[base + idx];
            sRaw[idx] = v;
            out_expert[base + idx] = v;
        }
        __syncthreads();
        for (int idx = tid; idx < RR*TT*4; idx += 256) {
            int q = idx % (TT*4);
            int k = q & 3, t = q >> 2;
            int row = idx / (TT*4);
            float v = sRaw[idx];
            if (k < 2 && t > 0) v -= sRaw[idx - 4];
            u16 hv = f2bf(v);
            inp[idx] = hv;
            if (t == 0) Hbuf[row*HST + 64 + k] = hv;
            if (q == 0) {
                Hbuf[row*HST + 68] = 0x3F80;                 // 1.0 (bias column)
                Hbuf[HBUF_U16 + row*HST + 68] = 0x3F80;
            }
        }
        __syncthreads();
    }

    float creg[4] = {0.f, 0.f, 0.f, 0.f};
    bf16x8 bw[4][3];

    auto build_bw = [&](const u16* wsW) {
#pragma unroll
        for (int g = 0; g < 4; ++g) {
            const u16* wr = wsW + (g*64 + jcol) * 72;
            bw[g][0] = *(const bf16x8*)(wr + quad*8);
            bw[g][1] = *(const bf16x8*)(wr + 32 + quad*8);
            if (quad == 0) {
                bw[g][2] = *(const bf16x8*)(wr + 64);
            } else {
                bf16x8 z;
#pragma unroll
                for (int j = 0; j < 8; ++j) z[j] = 0;
                bw[g][2] = z;
            }
        }
    };

    // one LSTM step: MFMA K=96 (h | x | 1 | 0) ; gates pre-scaled by log2e (g by 2log2e)
    auto lstm_step = [&](const u16* Hc, u16* Hn) {
        bf16x8 a0 = *(const bf16x8*)(Hc + lcol*HST + quad*8);
        bf16x8 a1 = *(const bf16x8*)(Hc + lcol*HST + 32 + quad*8);
        bf16x8 a2 = *(const bf16x8*)(Hc + lcol*HST + 64 + quad*8);
        f32x4 acc[4];
#pragma unroll
        for (int g = 0; g < 4; ++g) {
            f32x4 z = {0.f, 0.f, 0.f, 0.f};
            z = mfma16(a0, bw[g][0], z);
            z = mfma16(a1, bw[g][1], z);
            acc[g] = mfma16(a2, bw[g][2], z);
        }
#pragma unroll
        for (int r = 0; r < 4; ++r) {
            float Ei = ex2(-acc[0][r]);              // exp(-i)
            float Ef = ex2(-acc[1][r]);              // exp(-f)
            float Eg = ex2(-acc[2][r]);              // exp(-2g)
            float Eo = ex2(-acc[3][r]);              // exp(-o)
            float P = (1.f + Ei) * (1.f + Eg);
            float Q = 1.f + Ef;
            // c' = c*sigm(f) + sigm(i)*tanh(g) = [c*P + (1-Eg)*Q] / (P*Q)
            float num = fmaf(creg[r], P, (1.f - Eg) * Q);
            float c = num * rcpf(P * Q);
            creg[r] = c;
            float Ec = ex2(-2.f * L2E * c);          // exp(-2c)
            float h = (1.f - Ec) * rcpf((1.f + Eo) * (1.f + Ec));
            Hn[(quad*4 + r)*HST + jcol] = f2bf(h);
        }
    };

    // ---- encoder ----
    build_bw(ws + WS_WHHE);
    for (int stp = 0; stp < TT; ++stp) {
        const u16* Hc = Hbuf + (stp & 1) * HBUF_U16;
        u16* Hn = Hbuf + ((stp + 1) & 1) * HBUF_U16;
        lstm_step(Hc, Hn);
        if (tid < 64 && stp < TT-1) {
            int row = tid >> 2, k = tid & 3;
            Hn[row*HST + 64 + k] = inp[row*(TT*4) + (stp+1)*4 + k];
        }
        __syncthreads();
    }
    // hT in Hbuf[0] (TT even)

    // zero zBuf (pad cols >= 100 must be 0)
    {
        u32* zb = (u32*)zBuf;
        for (int idx = tid; idx < RR*136/2; idx += 256) zb[idx] = 0;
    }

    auto mlp_hidden = [&](const u16* inB, int inStride, u16* outB,
                          const u16* wsW, const float* bg) {
        float bv = bg[jcol];
        const u16* wr = wsW + jcol*64;
        bf16x8 bb0 = *(const bf16x8*)(wr + quad*8);
        bf16x8 bb1 = *(const bf16x8*)(wr + 32 + quad*8);
        f32x4 acc = {bv, bv, bv, bv};
        bf16x8 a0 = *(const bf16x8*)(inB + lcol*inStride + quad*8);
        bf16x8 a1 = *(const bf16x8*)(inB + lcol*inStride + 32 + quad*8);
        acc = mfma16(a0, bb0, acc);
        acc = mfma16(a1, bb1, acc);
#pragma unroll
        for (int r = 0; r < 4; ++r)
            outB[(quad*4 + r)*72 + jcol] = f2bf(leaky(acc[r]));
        __syncthreads();
    };

    auto mlp_final = [&](const u16* inB, const u16* wsW, const float* bg, int mode) {
#pragma unroll
        for (int ni = 0; ni < 2; ++ni) {
            int nt = wv + ni*4;
            if (nt >= 7) continue;
            int n = nt*16 + lcol;
            bool ok = (n < LL);
            float bv = ok ? bg[n] : 0.f;
            bf16x8 bb0, bb1;
            if (ok) {
                const u16* wr = wsW + n*64;
                bb0 = *(const bf16x8*)(wr + quad*8);
                bb1 = *(const bf16x8*)(wr + 32 + quad*8);
            } else {
#pragma unroll
                for (int j = 0; j < 8; ++j) { bb0[j] = 0; bb1[j] = 0; }
            }
            f32x4 acc = {bv, bv, bv, bv};
            bf16x8 a0 = *(const bf16x8*)(inB + lcol*72 + quad*8);
            bf16x8 a1 = *(const bf16x8*)(inB + lcol*72 + 32 + quad*8);
            acc = mfma16(a0, bb0, acc);
            acc = mfma16(a1, bb1, acc);
            if (ok) {
#pragma unroll
                for (int r = 0; r < 4; ++r) {
                    int m = quad*4 + r;
                    float vv = leaky(acc[r]);
                    size_t gi = (size_t)(b0g + m) * LL + n;
                    if (mode == 0) {
                        muB[m*LL + n] = f2bf(vv);
                        out_mu[gi] = vv;
                    } else {
                        out_lv[gi] = vv;
                        float mu = bf2f(muB[m*LL + n]);
                        float zv = tanh_(fmaf(eps[gi], __expf(0.5f * vv), mu));
                        zBuf[m*136 + n] = f2bf(zv);
                    }
                }
            }
        }
        __syncthreads();
    };

    // mean path (hT intact in Hbuf[0])
    mlp_hidden(Hbuf, HST, XB0, ws + WS_MWS, mean_bs);
    mlp_hidden(XB0, 72, XB1, ws + WS_MWS + 4096, mean_bs + 64);
    mlp_hidden(XB1, 72, XB0, ws + WS_MWS + 8192, mean_bs + 128);
    mlp_final(XB0, ws + WS_MWF, mean_bf, 0);
    // logvar path + fused reparameterization
    mlp_hidden(Hbuf, HST, XB0, ws + WS_LWS, lv_bs);
    mlp_hidden(XB0, 72, XB1, ws + WS_LWS + 4096, lv_bs + 64);
    mlp_hidden(XB1, 72, XB0, ws + WS_LWS + 8192, lv_bs + 128);
    mlp_final(XB0, ws + WS_LWF, lv_bf, 1);

    // ---- dh = z @ W_init^T + b_init -> Hbuf[0] + creg; decoder prep ----
    {
        float bv = b_init[jcol];
        const u16* wr = ws + WS_WINIT + jcol*128;
        f32x4 acc = {bv, bv, bv, bv};
#pragma unroll
        for (int kt = 0; kt < 4; ++kt) {
            bf16x8 az = *(const bf16x8*)(zBuf + lcol*136 + kt*32 + quad*8);
            bf16x8 bi = *(const bf16x8*)(wr + kt*32 + quad*8);
            acc = mfma16(az, bi, acc);
        }
#pragma unroll
        for (int r = 0; r < 4; ++r) {
            creg[r] = acc[r];
            Hbuf[(quad*4 + r)*HST + jcol] = f2bf(acc[r]);
        }
        __syncthreads();   // zBuf reads done before sPrev/sWc overwrite XB region
        if (tid < RR*4) {
            float v = init_state[b0g*4 + tid];
            sPrev[tid] = v;
            Hbuf[(tid >> 2)*HST + 64 + (tid & 3)] = f2bf(v);
        }
        if (tid < 128) sWc[tid] = W_c[tid];
        __syncthreads();
    }

    build_bw(ws + WS_WHHD);
    const float bc0 = b_c[0], bc1 = b_c[1];

    // ---- decoder ----
    for (int stp = 0; stp < TT; ++stp) {
        const u16* Hc = Hbuf + (stp & 1) * HBUF_U16;
        u16* Hn = Hbuf + ((stp + 1) & 1) * HBUF_U16;
        lstm_step(Hc, Hn);
        __syncthreads();
        if (tid < 64) {
            int row = tid >> 2, kq = tid & 3;
            const u16* hr = Hn + row*HST + kq*16;
            bf16x8 h0 = *(const bf16x8*)(hr);
            bf16x8 h1 = *(const bf16x8*)(hr + 8);
            const float4* w0 = (const float4*)(sWc + kq*16);
            const float4* w1 = (const float4*)(sWc + 64 + kq*16);
            float a0 = 0.f, a1 = 0.f;
#pragma unroll
            for (int p = 0; p < 2; ++p) {
                float4 wa = w0[2*p], wb = w0[2*p+1];
                float4 va = w1[2*p], vb = w1[2*p+1];
                bf16x8 hh = p ? h1 : h0;
                float hf[8];
#pragma unroll
                for (int j = 0; j < 8; ++j) hf[j] = bf2f((u16)hh[j]);
                a0 = fmaf(hf[0], wa.x, a0); a0 = fmaf(hf[1], wa.y, a0);
                a0 = fmaf(hf[2], wa.z, a0); a0 = fmaf(hf[3], wa.w, a0);
                a0 = fmaf(hf[4], wb.x, a0); a0 = fmaf(hf[5], wb.y, a0);
                a0 = fmaf(hf[6], wb.z, a0); a0 = fmaf(hf[7], wb.w, a0);
                a1 = fmaf(hf[0], va.x, a1); a1 = fmaf(hf[1], va.y, a1);
                a1 = fmaf(hf[2], va.z, a1); a1 = fmaf(hf[3], va.w, a1);
                a1 = fmaf(hf[4], vb.x, a1); a1 = fmaf(hf[5], vb.y, a1);
                a1 = fmaf(hf[6], vb.z, a1); a1 = fmaf(hf[7], vb.w, a1);
            }
            a0 += __shfl_xor(a0, 1); a1 += __shfl_xor(a1, 1);
            a0 += __shfl_xor(a0, 2); a1 += __shfl_xor(a1, 2);
            if (kq == 0) {
                float pedal = a0 + bc0;
                float steer = fminf(fmaxf(a1 + bc1, -0.5f), 0.5f);
                float4 pv = *(const float4*)(sPrev + row*4);
                float x = pv.x, y = pv.y, psi = pv.z, v = pv.w;
                float v1 = fminf(fmaxf(v + pedal * DTC, 0.f), 30.f);
                float sn, cs;
                __sincosf(psi, &sn, &cs);
                float psid = fminf(fmaxf(v * __tanf(steer) * 0.4f, -1.57f), 1.57f);
                float nx = fmaf(v * cs, DTC, x);
                float ny = fmaf(v * sn, DTC, y);
                float npsi = fmaf(psid, DTC, psi);
                float4 o; o.x = nx; o.y = ny; o.z = npsi; o.w = v1;
                *(float4*)(sPrev + row*4) = o;
                *(float4*)(out_recons + ((size_t)(b0g + row) * TT + stp) * 4) = o;
                u32 lo = (u32)f2bf(nx) | ((u32)f2bf(ny) << 16);
                u32 hi = (u32)f2bf(npsi) | ((u32)f2bf(v1) << 16);
                uint2 pk; pk.x = lo; pk.y = hi;
                *(uint2*)(Hn + row*HST + 64) = pk;
            }
        }
        __syncthreads();
    }
}

extern "C" void kernel_launch(void* const* d_in, const int* in_sizes, int n_in,
                              void* d_out, int out_size, void* d_ws, size_t ws_size,
                              hipStream_t stream) {
    (void)in_sizes; (void)n_in; (void)ws_size; (void)out_size;
    const float* expert    = (const float*)d_in[0];
    const float* init_st   = (const float*)d_in[1];
    const float* eps       = (const float*)d_in[2];
    const float* W_se      = (const float*)d_in[3];
    const float* b_se      = (const float*)d_in[4];
    const float* W_ih_e    = (const float*)d_in[5];
    const float* W_hh_e    = (const float*)d_in[6];
    const float* b_ih_e    = (const float*)d_in[7];
    const float* b_hh_e    = (const float*)d_in[8];
    const float* mean_Ws   = (const float*)d_in[9];
    const float* mean_bs   = (const float*)d_in[10];
    const float* mean_Wf   = (const float*)d_in[11];
    const float* mean_bf   = (const float*)d_in[12];
    const float* lv_Ws     = (const float*)d_in[13];
    const float* lv_bs     = (const float*)d_in[14];
    const float* lv_Wf     = (const float*)d_in[15];
    const float* lv_bf     = (const float*)d_in[16];
    const float* W_init    = (const float*)d_in[17];
    const float* b_init    = (const float*)d_in[18];
    const float* W_ih_d    = (const float*)d_in[19];
    const float* W_hh_d    = (const float*)d_in[20];
    const float* b_ih_d    = (const float*)d_in[21];
    const float* b_hh_d    = (const float*)d_in[22];
    const float* W_c       = (const float*)d_in[23];
    const float* b_c       = (const float*)d_in[24];

    float* out = (float*)d_out;
    const size_t n_traj = (size_t)B_TOT * TT * 4;
    const size_t n_lat  = (size_t)B_TOT * LL;
    float* out_recons = out;
    float* out_expert = out + n_traj;
    float* out_mu     = out + 2 * n_traj;
    float* out_lv     = out + 2 * n_traj + n_lat;

    u16* ws = (u16*)d_ws;

    setup_kernel<<<64, 256, 0, stream>>>(
        W_se, b_se, W_ih_e, W_hh_e, b_ih_e, b_hh_e,
        W_ih_d, W_hh_d, b_ih_d, b_hh_d,
        mean_Ws, lv_Ws, mean_Wf, lv_Wf, W_init, ws);

    vae_lstm_kernel<<<NBLK, 256, 0, stream>>>(
        expert, init_st, eps, ws,
        mean_bs, mean_bf, lv_bs, lv_bf, b_init, W_c, b_c,
        out_recons, out_expert, out_mu, out_lv);
}

// Round 8
// 219.185 us; speedup vs baseline: 1.6431x; 1.1894x over previous
//
#include <hip/hip_runtime.h>

typedef unsigned short u16;
typedef unsigned int u32;
typedef __attribute__((ext_vector_type(8))) short bf16x8;
typedef __attribute__((ext_vector_type(4))) float f32x4;

#define B_TOT 16384
#define RR 32
#define NBLK (B_TOT / RR)    // 512 blocks -> 2 blocks/CU
#define TT 30
#define LL 100
#define DTC 0.03f
#define L2E 1.44269504088896f

#define HST 104              // u16 stride of H rows (K=96 + pad), 16B aligned
#define HBUF_U16 (RR * HST)  // 3328 u16 per buffer

// ---- LDS byte offsets, total 38912 ----
#define OFF_H   0        // u16 [2][32][104] = 13312
#define OFF_XB  13312    // u16 [2][32][72] = 9216; sRaw f32[3840]=15360B aliases 13312..28671 @staging;
                         // sPrev f32[32][4] (+0) / sWc f32[2][64] (+512) alias here in decoder
#define OFF_Z   22528    // u16 [32][136] = 8704
#define OFF_U   31232    // 7680: inp bf16[32][30][4] (encoder) -> muB bf16[32][100] (MLP)
#define SMEM_SZ 38912

// ---- d_ws u16 offsets ----
#define WS_WHHE  0        // [256][72]: cols0-63 whh*scale, 64-67 fold, 68 bias, 69-71 zero
#define WS_WHHD  18432
#define WS_MWS   36864    // mean_Ws 3x[64][64]
#define WS_LWS   49152
#define WS_MWF   61440    // [100][64]
#define WS_LWF   67840
#define WS_WINIT 74240    // [64][128] zero-padded
#define WS_TOTAL 82432    // u16 (164864 bytes)

__device__ __forceinline__ float bf2f(u16 u) {
    union { u32 i; float f; } v; v.i = ((u32)u) << 16; return v.f;
}
__device__ __forceinline__ u16 f2bf(float f) {          // RNE (setup / one-shot paths)
    union { float f; u32 i; } v; v.f = f;
    return (u16)((v.i + 0x7FFFu + ((v.i >> 16) & 1u)) >> 16);
}
__device__ __forceinline__ u16 f2bf_t(float f) {        // truncation (hot paths)
    union { float f; u32 i; } v; v.f = f;
    return (u16)(v.i >> 16);
}
__device__ __forceinline__ float rcpf(float x) { return __builtin_amdgcn_rcpf(x); }
__device__ __forceinline__ float ex2(float x) { return __builtin_amdgcn_exp2f(x); }
__device__ __forceinline__ float tanh_(float x) {
    x = fminf(fmaxf(x, -15.f), 15.f);
    float e = __expf(2.f * x);
    return (e - 1.f) * rcpf(e + 1.f);
}
__device__ __forceinline__ float leaky(float x) { return x >= 0.f ? x : 0.01f * x; }
__device__ __forceinline__ f32x4 mfma16(bf16x8 a, bf16x8 b, f32x4 c) {
    return __builtin_amdgcn_mfma_f32_16x16x32_bf16(a, b, c, 0, 0, 0);
}

// ================= setup kernel: weight prep into d_ws =================
__global__ void setup_kernel(
    const float* __restrict__ W_se, const float* __restrict__ b_se,
    const float* __restrict__ W_ih_e, const float* __restrict__ W_hh_e,
    const float* __restrict__ b_ih_e, const float* __restrict__ b_hh_e,
    const float* __restrict__ W_ih_d, const float* __restrict__ W_hh_d,
    const float* __restrict__ b_ih_d, const float* __restrict__ b_hh_d,
    const float* __restrict__ mean_Ws, const float* __restrict__ lv_Ws,
    const float* __restrict__ mean_Wf, const float* __restrict__ lv_Wf,
    const float* __restrict__ W_init, u16* __restrict__ ws)
{
    const int gid = blockIdx.x * 256 + threadIdx.x;
    const int nth = gridDim.x * 256;
    // A: folded input-proj tails (512 dot-tasks)
    for (int i = gid; i < 512; i += nth) {
        int which = i >> 8, row = i & 255, g = row >> 6;
        float s = (g == 2) ? 2.f * L2E : L2E;
        const float* wih = (which ? W_ih_d : W_ih_e) + row * 64;
        float f0=0,f1=0,f2=0,f3=0,fb=0;
        for (int e = 0; e < 64; ++e) {
            float w = wih[e];
            f0 = fmaf(w, W_se[e*4+0], f0);
            f1 = fmaf(w, W_se[e*4+1], f1);
            f2 = fmaf(w, W_se[e*4+2], f2);
            f3 = fmaf(w, W_se[e*4+3], f3);
            fb = fmaf(w, b_se[e], fb);
        }
        fb += (which ? b_ih_d : b_ih_e)[row] + (which ? b_hh_d : b_hh_e)[row];
        u16* dst = ws + (which ? WS_WHHD : WS_WHHE) + row * 72 + 64;
        dst[0]=f2bf(f0*s); dst[1]=f2bf(f1*s); dst[2]=f2bf(f2*s); dst[3]=f2bf(f3*s);
        dst[4]=f2bf(fb*s); dst[5]=0; dst[6]=0; dst[7]=0;
    }
    // B: scaled W_hh rows
    for (int i = gid; i < 2*16384; i += nth) {
        int which = i >= 16384;
        int j = which ? i - 16384 : i;
        int row = j >> 6, k = j & 63, g = row >> 6;
        float s = (g == 2) ? 2.f * L2E : L2E;
        const float* whh = which ? W_hh_d : W_hh_e;
        ws[(which ? WS_WHHD : WS_WHHE) + row*72 + k] = f2bf(whh[j] * s);
    }
    // C: MLP hidden weights
    for (int i = gid; i < 12288; i += nth) {
        ws[WS_MWS + i] = f2bf(mean_Ws[i]);
        ws[WS_LWS + i] = f2bf(lv_Ws[i]);
    }
    // D: MLP final weights
    for (int i = gid; i < 6400; i += nth) {
        ws[WS_MWF + i] = f2bf(mean_Wf[i]);
        ws[WS_LWF + i] = f2bf(lv_Wf[i]);
    }
    // E: W_init zero-padded [64][128]
    for (int i = gid; i < 8192; i += nth) {
        int r = i >> 7, k = i & 127;
        ws[WS_WINIT + i] = (k < LL) ? f2bf(W_init[r*LL + k]) : (u16)0;
    }
}

// ================= main fused kernel =================
// RR=32: two independent 16-row chains per block (dual-chain ILP per wave).
// grid 512 -> 2 blocks/CU. launch_bounds(256,2) -> 256-reg budget, no spill
// (the (256,8) 64-reg cap spilled in round 5: FETCH 9->252 MB).
__global__ __launch_bounds__(256, 2) void vae_lstm_kernel(
    const float* __restrict__ expert, const float* __restrict__ init_state,
    const float* __restrict__ eps, const u16* __restrict__ ws,
    const float* __restrict__ mean_bs, const float* __restrict__ mean_bf,
    const float* __restrict__ lv_bs, const float* __restrict__ lv_bf,
    const float* __restrict__ b_init, const float* __restrict__ W_c,
    const float* __restrict__ b_c,
    float* __restrict__ out_recons, float* __restrict__ out_expert,
    float* __restrict__ out_mu, float* __restrict__ out_lv)
{
    const int tid = threadIdx.x;
    const int b0g = blockIdx.x * RR;
    const int wv = tid >> 6;
    const int lane = tid & 63;
    const int lcol = lane & 15;
    const int quad = lane >> 4;
    const int jcol = wv * 16 + lcol;

    __shared__ __align__(16) char smem[SMEM_SZ];
    u16* Hbuf  = (u16*)(smem + OFF_H);
    u16* XB0   = (u16*)(smem + OFF_XB);
    u16* XB1   = XB0 + RR * 72;
    u16* zBuf  = (u16*)(smem + OFF_Z);
    u16* inp   = (u16*)(smem + OFF_U);
    u16* muB   = (u16*)(smem + OFF_U);      // alias: inp dead after encoder
    float* sRaw  = (float*)(smem + OFF_XB); // staging alias
    float* sPrev = (float*)(smem + OFF_XB); // decoder alias (XB dead)
    float* sWc   = (float*)(smem + OFF_XB + 512);

    // ---- staging: load raw (+passthrough), zero H, rel-xy -> inp ----
    {
        const int base = b0g * (TT*4);
        u32* hz = (u32*)Hbuf;
        for (int idx = tid; idx < HBUF_U16; idx += 256) hz[idx] = 0;   // 13312 B = both buffers
        for (int idx = tid; idx < RR*TT*4; idx += 256) {
            float v = expert[base + idx];
            sRaw[idx] = v;
            out_expert[base + idx] = v;
        }
        __syncthreads();
        for (int idx = tid; idx < RR*TT*4; idx += 256) {
            int q = idx % (TT*4);
            int k = q & 3, t = q >> 2;
            int row = idx / (TT*4);
            float v = sRaw[idx];
            if (k < 2 && t > 0) v -= sRaw[idx - 4];
            u16 hv = f2bf(v);
            inp[idx] = hv;
            if (t == 0) Hbuf[row*HST + 64 + k] = hv;
            if (q == 0) {
                Hbuf[row*HST + 68] = 0x3F80;                 // 1.0 (bias column)
                Hbuf[HBUF_U16 + row*HST + 68] = 0x3F80;
            }
        }
        __syncthreads();
    }

    float creg[8];
#pragma unroll
    for (int u = 0; u < 8; ++u) creg[u] = 0.f;
    bf16x8 bw[4][3];

    auto build_bw = [&](const u16* wsW) {
#pragma unroll
        for (int g = 0; g < 4; ++g) {
            const u16* wr = wsW + (g*64 + jcol) * 72;
            bw[g][0] = *(const bf16x8*)(wr + quad*8);
            bw[g][1] = *(const bf16x8*)(wr + 32 + quad*8);
            if (quad == 0) {
                bw[g][2] = *(const bf16x8*)(wr + 64);
            } else {
                bf16x8 z;
#pragma unroll
                for (int j = 0; j < 8; ++j) z[j] = 0;
                bw[g][2] = z;
            }
        }
    };

    // one dual-chain LSTM step: 2 x (MFMA K=96 + gate epilogue); chains are
    // independent -> ILP fills transcendental / LDS latency.
    auto lstm_step = [&](const u16* Hc, u16* Hn) {
        f32x4 acc[2][4];
#pragma unroll
        for (int c = 0; c < 2; ++c) {
            bf16x8 a0 = *(const bf16x8*)(Hc + (c*16 + lcol)*HST + quad*8);
            bf16x8 a1 = *(const bf16x8*)(Hc + (c*16 + lcol)*HST + 32 + quad*8);
            bf16x8 a2 = *(const bf16x8*)(Hc + (c*16 + lcol)*HST + 64 + quad*8);
#pragma unroll
            for (int g = 0; g < 4; ++g) {
                f32x4 z = {0.f, 0.f, 0.f, 0.f};
                z = mfma16(a0, bw[g][0], z);
                z = mfma16(a1, bw[g][1], z);
                acc[c][g] = mfma16(a2, bw[g][2], z);
            }
        }
#pragma unroll
        for (int c = 0; c < 2; ++c)
#pragma unroll
            for (int r = 0; r < 4; ++r) {
                float Ei = ex2(-acc[c][0][r]);           // exp(-i)
                float Ef = ex2(-acc[c][1][r]);           // exp(-f)
                float Eg = ex2(-acc[c][2][r]);           // exp(-2g)
                float Eo = ex2(-acc[c][3][r]);           // exp(-o)
                float P = (1.f + Ei) * (1.f + Eg);
                float Q = 1.f + Ef;
                // c' = c*sigm(f) + sigm(i)*tanh(g) = [c*P + (1-Eg)*Q] / (P*Q)
                float num = fmaf(creg[c*4 + r], P, (1.f - Eg) * Q);
                float cc = num * rcpf(P * Q);
                creg[c*4 + r] = cc;
                float Ec = ex2(-2.f * L2E * cc);         // exp(-2c)
                float h = (1.f - Ec) * rcpf((1.f + Eo) * (1.f + Ec));
                Hn[(c*16 + quad*4 + r)*HST + jcol] = f2bf_t(h);
            }
    };

    // ---- encoder ----
    build_bw(ws + WS_WHHE);
    for (int stp = 0; stp < TT; ++stp) {
        const u16* Hc = Hbuf + (stp & 1) * HBUF_U16;
        u16* Hn = Hbuf + ((stp + 1) & 1) * HBUF_U16;
        lstm_step(Hc, Hn);
        if (tid < 128 && stp < TT-1) {
            int row = tid >> 2, k = tid & 3;
            Hn[row*HST + 64 + k] = inp[row*(TT*4) + (stp+1)*4 + k];
        }
        __syncthreads();
    }
    // hT in Hbuf[0] (TT even)

    // zero zBuf (pad cols >= 100 must be 0)
    {
        u32* zb = (u32*)zBuf;
        for (int idx = tid; idx < RR*136/2; idx += 256) zb[idx] = 0;
    }

    auto mlp_hidden = [&](const u16* inB, int inStride, u16* outB,
                          const u16* wsW, const float* bg) {
        float bv = bg[jcol];
        const u16* wr = wsW + jcol*64;
        bf16x8 bb0 = *(const bf16x8*)(wr + quad*8);
        bf16x8 bb1 = *(const bf16x8*)(wr + 32 + quad*8);
#pragma unroll
        for (int Mt = 0; Mt < 2; ++Mt) {
            f32x4 acc = {bv, bv, bv, bv};
            bf16x8 a0 = *(const bf16x8*)(inB + (Mt*16 + lcol)*inStride + quad*8);
            bf16x8 a1 = *(const bf16x8*)(inB + (Mt*16 + lcol)*inStride + 32 + quad*8);
            acc = mfma16(a0, bb0, acc);
            acc = mfma16(a1, bb1, acc);
#pragma unroll
            for (int r = 0; r < 4; ++r)
                outB[(Mt*16 + quad*4 + r)*72 + jcol] = f2bf_t(leaky(acc[r]));
        }
        __syncthreads();
    };

    auto mlp_final = [&](const u16* inB, const u16* wsW, const float* bg, int mode) {
#pragma unroll
        for (int ni = 0; ni < 2; ++ni) {
            int nt = wv + ni*4;
            if (nt >= 7) continue;
            int n = nt*16 + lcol;
            bool ok = (n < LL);
            float bv = ok ? bg[n] : 0.f;
            bf16x8 bb0, bb1;
            if (ok) {
                const u16* wr = wsW + n*64;
                bb0 = *(const bf16x8*)(wr + quad*8);
                bb1 = *(const bf16x8*)(wr + 32 + quad*8);
            } else {
#pragma unroll
                for (int j = 0; j < 8; ++j) { bb0[j] = 0; bb1[j] = 0; }
            }
#pragma unroll
            for (int Mt = 0; Mt < 2; ++Mt) {
                f32x4 acc = {bv, bv, bv, bv};
                bf16x8 a0 = *(const bf16x8*)(inB + (Mt*16 + lcol)*72 + quad*8);
                bf16x8 a1 = *(const bf16x8*)(inB + (Mt*16 + lcol)*72 + 32 + quad*8);
                acc = mfma16(a0, bb0, acc);
                acc = mfma16(a1, bb1, acc);
                if (ok) {
#pragma unroll
                    for (int r = 0; r < 4; ++r) {
                        int m = Mt*16 + quad*4 + r;
                        float vv = leaky(acc[r]);
                        size_t gi = (size_t)(b0g + m) * LL + n;
                        if (mode == 0) {
                            muB[m*LL + n] = f2bf_t(vv);
                            out_mu[gi] = vv;
                        } else {
                            out_lv[gi] = vv;
                            float mu = bf2f(muB[m*LL + n]);
                            float zv = tanh_(fmaf(eps[gi], __expf(0.5f * vv), mu));
                            zBuf[m*136 + n] = f2bf_t(zv);
                        }
                    }
                }
            }
        }
        __syncthreads();
    };

    // mean path (hT intact in Hbuf[0])
    mlp_hidden(Hbuf, HST, XB0, ws + WS_MWS, mean_bs);
    mlp_hidden(XB0, 72, XB1, ws + WS_MWS + 4096, mean_bs + 64);
    mlp_hidden(XB1, 72, XB0, ws + WS_MWS + 8192, mean_bs + 128);
    mlp_final(XB0, ws + WS_MWF, mean_bf, 0);
    // logvar path + fused reparameterization
    mlp_hidden(Hbuf, HST, XB0, ws + WS_LWS, lv_bs);
    mlp_hidden(XB0, 72, XB1, ws + WS_LWS + 4096, lv_bs + 64);
    mlp_hidden(XB1, 72, XB0, ws + WS_LWS + 8192, lv_bs + 128);
    mlp_final(XB0, ws + WS_LWF, lv_bf, 1);

    // ---- dh = z @ W_init^T + b_init -> Hbuf[0] + creg; decoder prep ----
    {
        float bv = b_init[jcol];
        const u16* wr = ws + WS_WINIT + jcol*128;
#pragma unroll
        for (int Mt = 0; Mt < 2; ++Mt) {
            f32x4 acc = {bv, bv, bv, bv};
#pragma unroll
            for (int kt = 0; kt < 4; ++kt) {
                bf16x8 az = *(const bf16x8*)(zBuf + (Mt*16 + lcol)*136 + kt*32 + quad*8);
                bf16x8 bi = *(const bf16x8*)(wr + kt*32 + quad*8);
                acc = mfma16(az, bi, acc);
            }
#pragma unroll
            for (int r = 0; r < 4; ++r) {
                creg[Mt*4 + r] = acc[r];
                Hbuf[(Mt*16 + quad*4 + r)*HST + jcol] = f2bf_t(acc[r]);
            }
        }
        __syncthreads();   // zBuf reads done before sPrev/sWc overwrite XB region
        if (tid < RR*4) {
            float v = init_state[b0g*4 + tid];
            sPrev[tid] = v;
            Hbuf[(tid >> 2)*HST + 64 + (tid & 3)] = f2bf(v);
        }
        if (tid < 128) sWc[tid] = W_c[tid];
        __syncthreads();
    }

    build_bw(ws + WS_WHHD);
    const float bc0 = b_c[0], bc1 = b_c[1];

    // ---- decoder ----
    for (int stp = 0; stp < TT; ++stp) {
        const u16* Hc = Hbuf + (stp & 1) * HBUF_U16;
        u16* Hn = Hbuf + ((stp + 1) & 1) * HBUF_U16;
        lstm_step(Hc, Hn);
        __syncthreads();
        if (tid < 128) {
            int row = tid >> 2, kq = tid & 3;
            const u16* hr = Hn + row*HST + kq*16;
            bf16x8 h0 = *(const bf16x8*)(hr);
            bf16x8 h1 = *(const bf16x8*)(hr + 8);
            const float4* w0 = (const float4*)(sWc + kq*16);
            const float4* w1 = (const float4*)(sWc + 64 + kq*16);
            float a0 = 0.f, a1 = 0.f;
#pragma unroll
            for (int p = 0; p < 2; ++p) {
                float4 wa = w0[2*p], wb = w0[2*p+1];
                float4 va = w1[2*p], vb = w1[2*p+1];
                bf16x8 hh = p ? h1 : h0;
                float hf[8];
#pragma unroll
                for (int j = 0; j < 8; ++j) hf[j] = bf2f((u16)hh[j]);
                a0 = fmaf(hf[0], wa.x, a0); a0 = fmaf(hf[1], wa.y, a0);
                a0 = fmaf(hf[2], wa.z, a0); a0 = fmaf(hf[3], wa.w, a0);
                a0 = fmaf(hf[4], wb.x, a0); a0 = fmaf(hf[5], wb.y, a0);
                a0 = fmaf(hf[6], wb.z, a0); a0 = fmaf(hf[7], wb.w, a0);
                a1 = fmaf(hf[0], va.x, a1); a1 = fmaf(hf[1], va.y, a1);
                a1 = fmaf(hf[2], va.z, a1); a1 = fmaf(hf[3], va.w, a1);
                a1 = fmaf(hf[4], vb.x, a1); a1 = fmaf(hf[5], vb.y, a1);
                a1 = fmaf(hf[6], vb.z, a1); a1 = fmaf(hf[7], vb.w, a1);
            }
            a0 += __shfl_xor(a0, 1); a1 += __shfl_xor(a1, 1);
            a0 += __shfl_xor(a0, 2); a1 += __shfl_xor(a1, 2);
            if (kq == 0) {
                float pedal = a0 + bc0;
                float steer = fminf(fmaxf(a1 + bc1, -0.5f), 0.5f);
                float4 pv = *(const float4*)(sPrev + row*4);
                float x = pv.x, y = pv.y, psi = pv.z, v = pv.w;
                float v1 = fminf(fmaxf(v + pedal * DTC, 0.f), 30.f);
                float sn, cs;
                __sincosf(psi, &sn, &cs);
                float psid = fminf(fmaxf(v * __tanf(steer) * 0.4f, -1.57f), 1.57f);
                float nx = fmaf(v * cs, DTC, x);
                float ny = fmaf(v * sn, DTC, y);
                float npsi = fmaf(psid, DTC, psi);
                float4 o; o.x = nx; o.y = ny; o.z = npsi; o.w = v1;
                *(float4*)(sPrev + row*4) = o;
                *(float4*)(out_recons + ((size_t)(b0g + row) * TT + stp) * 4) = o;
                u32 lo = (u32)f2bf(nx) | ((u32)f2bf(ny) << 16);
                u32 hi = (u32)f2bf(npsi) | ((u32)f2bf(v1) << 16);
                uint2 pk; pk.x = lo; pk.y = hi;
                *(uint2*)(Hn + row*HST + 64) = pk;
            }
        }
        __syncthreads();
    }
}

extern "C" void kernel_launch(void* const* d_in, const int* in_sizes, int n_in,
                              void* d_out, int out_size, void* d_ws, size_t ws_size,
                              hipStream_t stream) {
    (void)in_sizes; (void)n_in; (void)ws_size; (void)out_size;
    const float* expert    = (const float*)d_in[0];
    const float* init_st   = (const float*)d_in[1];
    const float* eps       = (const float*)d_in[2];
    const float* W_se      = (const float*)d_in[3];
    const float* b_se      = (const float*)d_in[4];
    const float* W_ih_e    = (const float*)d_in[5];
    const float* W_hh_e    = (const float*)d_in[6];
    const float* b_ih_e    = (const float*)d_in[7];
    const float* b_hh_e    = (const float*)d_in[8];
    const float* mean_Ws   = (const float*)d_in[9];
    const float* mean_bs   = (const float*)d_in[10];
    const float* mean_Wf   = (const float*)d_in[11];
    const float* mean_bf   = (const float*)d_in[12];
    const float* lv_Ws     = (const float*)d_in[13];
    const float* lv_bs     = (const float*)d_in[14];
    const float* lv_Wf     = (const float*)d_in[15];
    const float* lv_bf     = (const float*)d_in[16];
    const float* W_init    = (const float*)d_in[17];
    const float* b_init    = (const float*)d_in[18];
    const float* W_ih_d    = (const float*)d_in[19];
    const float* W_hh_d    = (const float*)d_in[20];
    const float* b_ih_d    = (const float*)d_in[21];
    const float* b_hh_d    = (const float*)d_in[22];
    const float* W_c       = (const float*)d_in[23];
    const float* b_c       = (const float*)d_in[24];

    float* out = (float*)d_out;
    const size_t n_traj = (size_t)B_TOT * TT * 4;
    const size_t n_lat  = (size_t)B_TOT * LL;
    float* out_recons = out;
    float* out_expert = out + n_traj;
    float* out_mu     = out + 2 * n_traj;
    float* out_lv     = out + 2 * n_traj + n_lat;

    u16* ws = (u16*)d_ws;

    setup_kernel<<<64, 256, 0, stream>>>(
        W_se, b_se, W_ih_e, W_hh_e, b_ih_e, b_hh_e,
        W_ih_d, W_hh_d, b_ih_d, b_hh_d,
        mean_Ws, lv_Ws, mean_Wf, lv_Wf, W_init, ws);

    vae_lstm_kernel<<<NBLK, 256, 0, stream>>>(
        expert, init_st, eps, ws,
        mean_bs, mean_bf, lv_bs, lv_bf, b_init, W_c, b_c,
        out_recons, out_expert, out_mu, out_lv);
}

// Round 9
// 209.682 us; speedup vs baseline: 1.7176x; 1.0453x over previous
//
#include <hip/hip_runtime.h>

typedef unsigned short u16;
typedef unsigned int u32;
typedef __attribute__((ext_vector_type(8))) short bf16x8;
typedef __attribute__((ext_vector_type(4))) float f32x4;

#define B_TOT 16384
#define RR 32
#define BLK 512
#define NBLK (B_TOT / RR)    // 512 blocks, 512 threads -> 2 blocks/CU, 16 waves/CU
#define TT 30
#define LL 100
#define DTC 0.03f
#define L2E 1.44269504088896f

#define HST 104              // u16 stride of H rows (K=96 + pad), 16B aligned
#define HBUF_U16 (RR * HST)  // 3328 u16 per buffer

// ---- LDS byte offsets, total 38912 ----
#define OFF_H   0        // u16 [2][32][104] = 13312
#define OFF_XB  13312    // u16 [2][32][72] = 9216; sRaw f32[3840]=15360B aliases @staging;
                         // sPrev f32[32][4] (+0) / sWc f32[2][64] (+512) alias in decoder
#define OFF_Z   22528    // u16 [32][136] = 8704
#define OFF_U   31232    // 7680: inp bf16[32][30][4] (encoder) -> muB bf16[32][100] (MLP)
#define SMEM_SZ 38912

// ---- d_ws u16 offsets ----
#define WS_WHHE  0        // [256][72]: cols0-63 whh*scale, 64-67 fold, 68 bias, 69-71 zero
#define WS_WHHD  18432
#define WS_MWS   36864    // mean_Ws 3x[64][64]
#define WS_LWS   49152
#define WS_MWF   61440    // [100][64]
#define WS_LWF   67840
#define WS_WINIT 74240    // [64][128] zero-padded
#define WS_TOTAL 82432    // u16 (164864 bytes)

__device__ __forceinline__ float bf2f(u16 u) {
    union { u32 i; float f; } v; v.i = ((u32)u) << 16; return v.f;
}
__device__ __forceinline__ u16 f2bf(float f) {          // RNE (setup / one-shot paths)
    union { float f; u32 i; } v; v.f = f;
    return (u16)((v.i + 0x7FFFu + ((v.i >> 16) & 1u)) >> 16);
}
__device__ __forceinline__ u16 f2bf_t(float f) {        // truncation (hot paths)
    union { float f; u32 i; } v; v.f = f;
    return (u16)(v.i >> 16);
}
__device__ __forceinline__ float rcpf(float x) { return __builtin_amdgcn_rcpf(x); }
__device__ __forceinline__ float ex2(float x) { return __builtin_amdgcn_exp2f(x); }
__device__ __forceinline__ float tanh_(float x) {
    x = fminf(fmaxf(x, -15.f), 15.f);
    float e = __expf(2.f * x);
    return (e - 1.f) * rcpf(e + 1.f);
}
__device__ __forceinline__ float leaky(float x) { return x >= 0.f ? x : 0.01f * x; }
__device__ __forceinline__ f32x4 mfma16(bf16x8 a, bf16x8 b, f32x4 c) {
    return __builtin_amdgcn_mfma_f32_16x16x32_bf16(a, b, c, 0, 0, 0);
}

// ================= setup kernel: weight prep into d_ws =================
__global__ void setup_kernel(
    const float* __restrict__ W_se, const float* __restrict__ b_se,
    const float* __restrict__ W_ih_e, const float* __restrict__ W_hh_e,
    const float* __restrict__ b_ih_e, const float* __restrict__ b_hh_e,
    const float* __restrict__ W_ih_d, const float* __restrict__ W_hh_d,
    const float* __restrict__ b_ih_d, const float* __restrict__ b_hh_d,
    const float* __restrict__ mean_Ws, const float* __restrict__ lv_Ws,
    const float* __restrict__ mean_Wf, const float* __restrict__ lv_Wf,
    const float* __restrict__ W_init, u16* __restrict__ ws)
{
    const int gid = blockIdx.x * 256 + threadIdx.x;
    const int nth = gridDim.x * 256;
    // A: folded input-proj tails (512 dot-tasks)
    for (int i = gid; i < 512; i += nth) {
        int which = i >> 8, row = i & 255, g = row >> 6;
        float s = (g == 2) ? 2.f * L2E : L2E;
        const float* wih = (which ? W_ih_d : W_ih_e) + row * 64;
        float f0=0,f1=0,f2=0,f3=0,fb=0;
        for (int e = 0; e < 64; ++e) {
            float w = wih[e];
            f0 = fmaf(w, W_se[e*4+0], f0);
            f1 = fmaf(w, W_se[e*4+1], f1);
            f2 = fmaf(w, W_se[e*4+2], f2);
            f3 = fmaf(w, W_se[e*4+3], f3);
            fb = fmaf(w, b_se[e], fb);
        }
        fb += (which ? b_ih_d : b_ih_e)[row] + (which ? b_hh_d : b_hh_e)[row];
        u16* dst = ws + (which ? WS_WHHD : WS_WHHE) + row * 72 + 64;
        dst[0]=f2bf(f0*s); dst[1]=f2bf(f1*s); dst[2]=f2bf(f2*s); dst[3]=f2bf(f3*s);
        dst[4]=f2bf(fb*s); dst[5]=0; dst[6]=0; dst[7]=0;
    }
    // B: scaled W_hh rows
    for (int i = gid; i < 2*16384; i += nth) {
        int which = i >= 16384;
        int j = which ? i - 16384 : i;
        int row = j >> 6, k = j & 63, g = row >> 6;
        float s = (g == 2) ? 2.f * L2E : L2E;
        const float* whh = which ? W_hh_d : W_hh_e;
        ws[(which ? WS_WHHD : WS_WHHE) + row*72 + k] = f2bf(whh[j] * s);
    }
    // C: MLP hidden weights
    for (int i = gid; i < 12288; i += nth) {
        ws[WS_MWS + i] = f2bf(mean_Ws[i]);
        ws[WS_LWS + i] = f2bf(lv_Ws[i]);
    }
    // D: MLP final weights
    for (int i = gid; i < 6400; i += nth) {
        ws[WS_MWF + i] = f2bf(mean_Wf[i]);
        ws[WS_LWF + i] = f2bf(lv_Wf[i]);
    }
    // E: W_init zero-padded [64][128]
    for (int i = gid; i < 8192; i += nth) {
        int r = i >> 7, k = i & 127;
        ws[WS_WINIT + i] = (k < LL) ? f2bf(W_init[r*LL + k]) : (u16)0;
    }
}

// ================= main fused kernel =================
// BLK=512: 8 waves; wave w owns M-tile (w>>2) and gate-columns ((w&3)*16 + lcol).
// 2 blocks/CU -> 16 waves/CU (4/SIMD) to fill transcendental-chain stalls.
// launch_bounds(512,4) -> 128-reg budget; kernel needs ~56 -> no spill
// (the (256,8) 64-reg cap spilled in round 5: FETCH 9->252 MB).
__global__ __launch_bounds__(BLK, 4) void vae_lstm_kernel(
    const float* __restrict__ expert, const float* __restrict__ init_state,
    const float* __restrict__ eps, const u16* __restrict__ ws,
    const float* __restrict__ mean_bs, const float* __restrict__ mean_bf,
    const float* __restrict__ lv_bs, const float* __restrict__ lv_bf,
    const float* __restrict__ b_init, const float* __restrict__ W_c,
    const float* __restrict__ b_c,
    float* __restrict__ out_recons, float* __restrict__ out_expert,
    float* __restrict__ out_mu, float* __restrict__ out_lv)
{
    const int tid = threadIdx.x;
    const int b0g = blockIdx.x * RR;
    const int wv = tid >> 6;          // 0..7
    const int Mt = wv >> 2;           // M-tile (batch rows Mt*16..Mt*16+15)
    const int wsub = wv & 3;          // column-group within the gate space
    const int lane = tid & 63;
    const int lcol = lane & 15;
    const int quad = lane >> 4;
    const int jcol = wsub * 16 + lcol;

    __shared__ __align__(16) char smem[SMEM_SZ];
    u16* Hbuf  = (u16*)(smem + OFF_H);
    u16* XB0   = (u16*)(smem + OFF_XB);
    u16* XB1   = XB0 + RR * 72;
    u16* zBuf  = (u16*)(smem + OFF_Z);
    u16* inp   = (u16*)(smem + OFF_U);
    u16* muB   = (u16*)(smem + OFF_U);      // alias: inp dead after encoder
    float* sRaw  = (float*)(smem + OFF_XB); // staging alias
    float* sPrev = (float*)(smem + OFF_XB); // decoder alias (XB dead)
    float* sWc   = (float*)(smem + OFF_XB + 512);

    // ---- staging: load raw (+passthrough), zero H, rel-xy -> inp ----
    {
        const int base = b0g * (TT*4);
        u32* hz = (u32*)Hbuf;
        for (int idx = tid; idx < HBUF_U16; idx += BLK) hz[idx] = 0;   // 13312 B = both buffers
        for (int idx = tid; idx < RR*TT*4; idx += BLK) {
            float v = expert[base + idx];
            sRaw[idx] = v;
            out_expert[base + idx] = v;
        }
        __syncthreads();
        for (int idx = tid; idx < RR*TT*4; idx += BLK) {
            int q = idx % (TT*4);
            int k = q & 3, t = q >> 2;
            int row = idx / (TT*4);
            float v = sRaw[idx];
            if (k < 2 && t > 0) v -= sRaw[idx - 4];
            u16 hv = f2bf(v);
            inp[idx] = hv;
            if (t == 0) Hbuf[row*HST + 64 + k] = hv;
            if (q == 0) {
                Hbuf[row*HST + 68] = 0x3F80;                 // 1.0 (bias column)
                Hbuf[HBUF_U16 + row*HST + 68] = 0x3F80;
            }
        }
        __syncthreads();
    }

    float creg[4] = {0.f, 0.f, 0.f, 0.f};
    bf16x8 bw[4][3];

    auto build_bw = [&](const u16* wsW) {
#pragma unroll
        for (int g = 0; g < 4; ++g) {
            const u16* wr = wsW + (g*64 + jcol) * 72;
            bw[g][0] = *(const bf16x8*)(wr + quad*8);
            bw[g][1] = *(const bf16x8*)(wr + 32 + quad*8);
            if (quad == 0) {
                bw[g][2] = *(const bf16x8*)(wr + 64);
            } else {
                bf16x8 z;
#pragma unroll
                for (int j = 0; j < 8; ++j) z[j] = 0;
                bw[g][2] = z;
            }
        }
    };

    // one LSTM step for this wave's M-tile: MFMA K=96 + fused gate epilogue
    auto lstm_step = [&](const u16* Hc, u16* Hn) {
        const u16* hrow = Hc + (Mt*16 + lcol)*HST;
        bf16x8 a0 = *(const bf16x8*)(hrow + quad*8);
        bf16x8 a1 = *(const bf16x8*)(hrow + 32 + quad*8);
        bf16x8 a2 = *(const bf16x8*)(hrow + 64 + quad*8);
        f32x4 acc[4];
#pragma unroll
        for (int g = 0; g < 4; ++g) {
            f32x4 z = {0.f, 0.f, 0.f, 0.f};
            z = mfma16(a0, bw[g][0], z);
            z = mfma16(a1, bw[g][1], z);
            acc[g] = mfma16(a2, bw[g][2], z);
        }
#pragma unroll
        for (int r = 0; r < 4; ++r) {
            float Ei = ex2(-acc[0][r]);              // exp(-i)
            float Ef = ex2(-acc[1][r]);              // exp(-f)
            float Eg = ex2(-acc[2][r]);              // exp(-2g)
            float Eo = ex2(-acc[3][r]);              // exp(-o)
            float P = (1.f + Ei) * (1.f + Eg);
            float Q = 1.f + Ef;
            // c' = c*sigm(f) + sigm(i)*tanh(g) = [c*P + (1-Eg)*Q] / (P*Q)
            float num = fmaf(creg[r], P, (1.f - Eg) * Q);
            float cc = num * rcpf(P * Q);
            creg[r] = cc;
            float Ec = ex2(-2.f * L2E * cc);         // exp(-2c)
            float h = (1.f - Ec) * rcpf((1.f + Eo) * (1.f + Ec));
            Hn[(Mt*16 + quad*4 + r)*HST + jcol] = f2bf_t(h);
        }
    };

    // ---- encoder ----
    build_bw(ws + WS_WHHE);
    for (int stp = 0; stp < TT; ++stp) {
        const u16* Hc = Hbuf + (stp & 1) * HBUF_U16;
        u16* Hn = Hbuf + ((stp + 1) & 1) * HBUF_U16;
        lstm_step(Hc, Hn);
        if (tid < 128 && stp < TT-1) {
            int row = tid >> 2, k = tid & 3;
            Hn[row*HST + 64 + k] = inp[row*(TT*4) + (stp+1)*4 + k];
        }
        __syncthreads();
    }
    // hT in Hbuf[0] (TT even)

    // zero zBuf (pad cols >= 100 must be 0)
    {
        u32* zb = (u32*)zBuf;
        for (int idx = tid; idx < RR*136/2; idx += BLK) zb[idx] = 0;
    }

    auto mlp_hidden = [&](const u16* inB, int inStride, u16* outB,
                          const u16* wsW, const float* bg) {
        float bv = bg[jcol];
        const u16* wr = wsW + jcol*64;
        bf16x8 bb0 = *(const bf16x8*)(wr + quad*8);
        bf16x8 bb1 = *(const bf16x8*)(wr + 32 + quad*8);
        f32x4 acc = {bv, bv, bv, bv};
        bf16x8 a0 = *(const bf16x8*)(inB + (Mt*16 + lcol)*inStride + quad*8);
        bf16x8 a1 = *(const bf16x8*)(inB + (Mt*16 + lcol)*inStride + 32 + quad*8);
        acc = mfma16(a0, bb0, acc);
        acc = mfma16(a1, bb1, acc);
#pragma unroll
        for (int r = 0; r < 4; ++r)
            outB[(Mt*16 + quad*4 + r)*72 + jcol] = f2bf_t(leaky(acc[r]));
        __syncthreads();
    };

    // 14 tasks (7 n-tiles x 2 M-tiles) over 8 waves: wave w takes t=w and t=w+8
    auto mlp_final = [&](const u16* inB, const u16* wsW, const float* bg, int mode) {
#pragma unroll
        for (int ti = 0; ti < 2; ++ti) {
            int t = wv + ti*8;
            if (t >= 14) continue;
            int nt = t >> 1, Mtl = t & 1;
            int n = nt*16 + lcol;
            bool ok = (n < LL);
            float bv = ok ? bg[n] : 0.f;
            bf16x8 bb0, bb1;
            if (ok) {
                const u16* wr = wsW + n*64;
                bb0 = *(const bf16x8*)(wr + quad*8);
                bb1 = *(const bf16x8*)(wr + 32 + quad*8);
            } else {
#pragma unroll
                for (int j = 0; j < 8; ++j) { bb0[j] = 0; bb1[j] = 0; }
            }
            f32x4 acc = {bv, bv, bv, bv};
            bf16x8 a0 = *(const bf16x8*)(inB + (Mtl*16 + lcol)*72 + quad*8);
            bf16x8 a1 = *(const bf16x8*)(inB + (Mtl*16 + lcol)*72 + 32 + quad*8);
            acc = mfma16(a0, bb0, acc);
            acc = mfma16(a1, bb1, acc);
            if (ok) {
#pragma unroll
                for (int r = 0; r < 4; ++r) {
                    int m = Mtl*16 + quad*4 + r;
                    float vv = leaky(acc[r]);
                    size_t gi = (size_t)(b0g + m) * LL + n;
                    if (mode == 0) {
                        muB[m*LL + n] = f2bf_t(vv);
                        out_mu[gi] = vv;
                    } else {
                        out_lv[gi] = vv;
                        float mu = bf2f(muB[m*LL + n]);
                        float zv = tanh_(fmaf(eps[gi], __expf(0.5f * vv), mu));
                        zBuf[m*136 + n] = f2bf_t(zv);
                    }
                }
            }
        }
        __syncthreads();
    };

    // mean path (hT intact in Hbuf[0])
    mlp_hidden(Hbuf, HST, XB0, ws + WS_MWS, mean_bs);
    mlp_hidden(XB0, 72, XB1, ws + WS_MWS + 4096, mean_bs + 64);
    mlp_hidden(XB1, 72, XB0, ws + WS_MWS + 8192, mean_bs + 128);
    mlp_final(XB0, ws + WS_MWF, mean_bf, 0);
    // logvar path + fused reparameterization
    mlp_hidden(Hbuf, HST, XB0, ws + WS_LWS, lv_bs);
    mlp_hidden(XB0, 72, XB1, ws + WS_LWS + 4096, lv_bs + 64);
    mlp_hidden(XB1, 72, XB0, ws + WS_LWS + 8192, lv_bs + 128);
    mlp_final(XB0, ws + WS_LWF, lv_bf, 1);

    // ---- dh = z @ W_init^T + b_init -> Hbuf[0] + creg; decoder prep ----
    {
        float bv = b_init[jcol];
        const u16* wr = ws + WS_WINIT + jcol*128;
        f32x4 acc = {bv, bv, bv, bv};
#pragma unroll
        for (int kt = 0; kt < 4; ++kt) {
            bf16x8 az = *(const bf16x8*)(zBuf + (Mt*16 + lcol)*136 + kt*32 + quad*8);
            bf16x8 bi = *(const bf16x8*)(wr + kt*32 + quad*8);
            acc = mfma16(az, bi, acc);
        }
#pragma unroll
        for (int r = 0; r < 4; ++r) {
            creg[r] = acc[r];
            Hbuf[(Mt*16 + quad*4 + r)*HST + jcol] = f2bf_t(acc[r]);
        }
        __syncthreads();   // zBuf reads done before sPrev/sWc overwrite XB region
        if (tid < RR*4) {
            float v = init_state[b0g*4 + tid];
            sPrev[tid] = v;
            Hbuf[(tid >> 2)*HST + 64 + (tid & 3)] = f2bf(v);
        }
        if (tid < 128) sWc[tid] = W_c[tid];
        __syncthreads();
    }

    build_bw(ws + WS_WHHD);
    const float bc0 = b_c[0], bc1 = b_c[1];

    // ---- decoder ----
    for (int stp = 0; stp < TT; ++stp) {
        const u16* Hc = Hbuf + (stp & 1) * HBUF_U16;
        u16* Hn = Hbuf + ((stp + 1) & 1) * HBUF_U16;
        lstm_step(Hc, Hn);
        __syncthreads();
        if (tid < 128) {
            int row = tid >> 2, kq = tid & 3;
            const u16* hr = Hn + row*HST + kq*16;
            bf16x8 h0 = *(const bf16x8*)(hr);
            bf16x8 h1 = *(const bf16x8*)(hr + 8);
            const float4* w0 = (const float4*)(sWc + kq*16);
            const float4* w1 = (const float4*)(sWc + 64 + kq*16);
            float a0 = 0.f, a1 = 0.f;
#pragma unroll
            for (int p = 0; p < 2; ++p) {
                float4 wa = w0[2*p], wb = w0[2*p+1];
                float4 va = w1[2*p], vb = w1[2*p+1];
                bf16x8 hh = p ? h1 : h0;
                float hf[8];
#pragma unroll
                for (int j = 0; j < 8; ++j) hf[j] = bf2f((u16)hh[j]);
                a0 = fmaf(hf[0], wa.x, a0); a0 = fmaf(hf[1], wa.y, a0);
                a0 = fmaf(hf[2], wa.z, a0); a0 = fmaf(hf[3], wa.w, a0);
                a0 = fmaf(hf[4], wb.x, a0); a0 = fmaf(hf[5], wb.y, a0);
                a0 = fmaf(hf[6], wb.z, a0); a0 = fmaf(hf[7], wb.w, a0);
                a1 = fmaf(hf[0], va.x, a1); a1 = fmaf(hf[1], va.y, a1);
                a1 = fmaf(hf[2], va.z, a1); a1 = fmaf(hf[3], va.w, a1);
                a1 = fmaf(hf[4], vb.x, a1); a1 = fmaf(hf[5], vb.y, a1);
                a1 = fmaf(hf[6], vb.z, a1); a1 = fmaf(hf[7], vb.w, a1);
            }
            a0 += __shfl_xor(a0, 1); a1 += __shfl_xor(a1, 1);
            a0 += __shfl_xor(a0, 2); a1 += __shfl_xor(a1, 2);
            if (kq == 0) {
                float pedal = a0 + bc0;
                float steer = fminf(fmaxf(a1 + bc1, -0.5f), 0.5f);
                float4 pv = *(const float4*)(sPrev + row*4);
                float x = pv.x, y = pv.y, psi = pv.z, v = pv.w;
                float v1 = fminf(fmaxf(v + pedal * DTC, 0.f), 30.f);
                float sn, cs;
                __sincosf(psi, &sn, &cs);
                float psid = fminf(fmaxf(v * __tanf(steer) * 0.4f, -1.57f), 1.57f);
                float nx = fmaf(v * cs, DTC, x);
                float ny = fmaf(v * sn, DTC, y);
                float npsi = fmaf(psid, DTC, psi);
                float4 o; o.x = nx; o.y = ny; o.z = npsi; o.w = v1;
                *(float4*)(sPrev + row*4) = o;
                *(float4*)(out_recons + ((size_t)(b0g + row) * TT + stp) * 4) = o;
                u32 lo = (u32)f2bf(nx) | ((u32)f2bf(ny) << 16);
                u32 hi = (u32)f2bf(npsi) | ((u32)f2bf(v1) << 16);
                uint2 pk; pk.x = lo; pk.y = hi;
                *(uint2*)(Hn + row*HST + 64) = pk;
            }
        }
        __syncthreads();
    }
}

extern "C" void kernel_launch(void* const* d_in, const int* in_sizes, int n_in,
                              void* d_out, int out_size, void* d_ws, size_t ws_size,
                              hipStream_t stream) {
    (void)in_sizes; (void)n_in; (void)ws_size; (void)out_size;
    const float* expert    = (const float*)d_in[0];
    const float* init_st   = (const float*)d_in[1];
    const float* eps       = (const float*)d_in[2];
    const float* W_se      = (const float*)d_in[3];
    const float* b_se      = (const float*)d_in[4];
    const float* W_ih_e    = (const float*)d_in[5];
    const float* W_hh_e    = (const float*)d_in[6];
    const float* b_ih_e    = (const float*)d_in[7];
    const float* b_hh_e    = (const float*)d_in[8];
    const float* mean_Ws   = (const float*)d_in[9];
    const float* mean_bs   = (const float*)d_in[10];
    const float* mean_Wf   = (const float*)d_in[11];
    const float* mean_bf   = (const float*)d_in[12];
    const float* lv_Ws     = (const float*)d_in[13];
    const float* lv_bs     = (const float*)d_in[14];
    const float* lv_Wf     = (const float*)d_in[15];
    const float* lv_bf     = (const float*)d_in[16];
    const float* W_init    = (const float*)d_in[17];
    const float* b_init    = (const float*)d_in[18];
    const float* W_ih_d    = (const float*)d_in[19];
    const float* W_hh_d    = (const float*)d_in[20];
    const float* b_ih_d    = (const float*)d_in[21];
    const float* b_hh_d    = (const float*)d_in[22];
    const float* W_c       = (const float*)d_in[23];
    const float* b_c       = (const float*)d_in[24];

    float* out = (float*)d_out;
    const size_t n_traj = (size_t)B_TOT * TT * 4;
    const size_t n_lat  = (size_t)B_TOT * LL;
    float* out_recons = out;
    float* out_expert = out + n_traj;
    float* out_mu     = out + 2 * n_traj;
    float* out_lv     = out + 2 * n_traj + n_lat;

    u16* ws = (u16*)d_ws;

    setup_kernel<<<64, 256, 0, stream>>>(
        W_se, b_se, W_ih_e, W_hh_e, b_ih_e, b_hh_e,
        W_ih_d, W_hh_d, b_ih_d, b_hh_d,
        mean_Ws, lv_Ws, mean_Wf, lv_Wf, W_init, ws);

    vae_lstm_kernel<<<NBLK, BLK, 0, stream>>>(
        expert, init_st, eps, ws,
        mean_bs, mean_bf, lv_bs, lv_bf, b_init, W_c, b_c,
        out_recons, out_expert, out_mu, out_lv);
}